// Round 12
// baseline (437.029 us; speedup 1.0000x reference)
//
#include <hip/hip_runtime.h>

using u16 = unsigned short;
using u32 = unsigned int;
typedef float f32x4 __attribute__((ext_vector_type(4)));
typedef float f32x2 __attribute__((ext_vector_type(2)));
typedef short s16x8 __attribute__((ext_vector_type(8)));
typedef u32   u32x2 __attribute__((ext_vector_type(2)));
typedef u32   u32x4 __attribute__((ext_vector_type(4)));

__device__ __forceinline__ u16 f2bf(float f) {
  u32 u = __float_as_uint(f);
  u += 0x7fffu + ((u >> 16) & 1u);
  return (u16)(u >> 16);
}
__device__ __forceinline__ float bf2f(u16 h) {
  return __uint_as_float(((u32)h) << 16);
}

__global__ void ROEN_Final_33526514713351_kernel() {}

// Fragment layout for eS2/vb2: row r, u32 j in [0,64): lo16 = dim 32*(j>>4)+(j&15),
// hi16 = that dim + 16.  Head h lives at u32s (h>>1)*16+j with shift (h&1)*16.

// ---------- stage 0+4: weight prep (blocks 0-4) + count zero (blocks 5+) ----------
__global__ void roen_prep_w(const float* __restrict__ W0, const float* __restrict__ W1,
                            const float* __restrict__ W2, const float* __restrict__ W3,
                            const float* __restrict__ W4, u16* __restrict__ Wt,
                            int* __restrict__ count, int N, float* __restrict__ dbg) {
  int b = blockIdx.x;
  if (b < 5) {
    if (b == 0 && threadIdx.x == 0) dbg[4] = 1004.0f;
    const float* W = (b == 0) ? W0 : (b == 1) ? W1 : (b == 2) ? W2 : (b == 3) ? W3 : W4;
    for (int idx = threadIdx.x; idx < 16384; idx += 256) {
      int n = idx >> 7, k = idx & 127;
      Wt[b * 16384 + idx] = f2bf(W[k * 128 + n]);
    }
  } else {
    int i = (b - 5) * 256 + threadIdx.x;
    if (i == 0) dbg[0] = 1000.0f;
    if (i < N) count[i] = 0;
  }
}

// ---------- stage 1: histogram + per-edge rank ----------
__global__ void roen_hist(const int* __restrict__ ei, int E, int* __restrict__ count,
                          int* __restrict__ rank, float* __restrict__ dbg) {
  int i = blockIdx.x * 256 + threadIdx.x;
  if (i == 0) dbg[1] = 1001.0f;
  if (i < E) rank[i] = atomicAdd(&count[ei[E + i]], 1);
}

// ---------- stage 2: exclusive scan, coalesced 1024-wide tiles + wave shfl-scan ----------
__global__ __launch_bounds__(1024) void roen_scan(const int* __restrict__ count, int N,
                                                  int* __restrict__ off,
                                                  float* __restrict__ dbg) {
  __shared__ int wsum[16];
  __shared__ int carrys;
  int tid = threadIdx.x, lane = tid & 63, wv = tid >> 6;
  if (tid == 0) { dbg[2] = 1002.0f; carrys = 0; }
  __syncthreads();
  for (int base = 0; base < N; base += 1024) {
    int i = base + tid;
    int v = (i < N) ? count[i] : 0;
    int x = v;
#pragma unroll
    for (int s = 1; s < 64; s <<= 1) {
      int t = __shfl_up(x, s);
      if (lane >= s) x += t;
    }
    if (lane == 63) wsum[wv] = x;
    __syncthreads();
    if (wv == 0 && lane < 16) {
      int y = wsum[lane];
#pragma unroll
      for (int s = 1; s < 16; s <<= 1) {
        int t = __shfl_up(y, s);
        if (lane >= s) y += t;
      }
      wsum[lane] = y;
    }
    __syncthreads();
    int wbase = (wv == 0) ? 0 : wsum[wv - 1];
    int incl = x + wbase + carrys;
    if (i < N) off[i] = incl - v;
    __syncthreads();
    if (tid == 1023) carrys = incl;
    __syncthreads();
  }
  if (tid == 0) off[N] = carrys;
}

// ---------- stage 3: scatter without atomics: pos = off[dst] + rank ----------
__global__ void roen_scatter(const int* __restrict__ ei, const int* __restrict__ off,
                             const int* __restrict__ rank, int E,
                             int* __restrict__ inv, int* __restrict__ srcS,
                             float* __restrict__ dbg) {
  int i = blockIdx.x * 256 + threadIdx.x;
  if (i == 0) dbg[3] = 1003.0f;
  if (i < E) {
    int d = ei[E + i];
    int p = off[d] + rank[i];
    inv[i] = p;
    srcS[p] = ei[i];
  }
}

// ---------- stage 5: fused q/k/v GEMM; q,k row layout, v fragment layout ----------
__global__ __launch_bounds__(256) void roen_gemm_qkv(const float* __restrict__ x,
                                                     const u16* __restrict__ Wt,
                                                     u16* __restrict__ qb, u16* __restrict__ kb,
                                                     u32* __restrict__ vb2, int M,
                                                     float* __restrict__ dbg) {
  __shared__ u16 As[64 * 128];
  const int tid = threadIdx.x;
  if (blockIdx.x == 0 && tid == 0) dbg[5] = 1005.0f;
  const long brow = (long)blockIdx.x * 64;

  {
    f32x4 tmp[8];
#pragma unroll
    for (int j = 0; j < 8; ++j) {
      int idx = j * 256 + tid;
      int row = idx >> 5;
      int c4 = (idx & 31) * 4;
      long grow = brow + row;
      f32x4 a = {0.f, 0.f, 0.f, 0.f};
      if (grow < M) a = *(const f32x4*)(x + grow * 128 + c4);
      tmp[j] = a;
    }
#pragma unroll
    for (int j = 0; j < 8; ++j) {
      int idx = j * 256 + tid;
      int row = idx >> 5;
      int c4 = (idx & 31) * 4;
      u32 lo = ((u32)f2bf(tmp[j][1]) << 16) | (u32)f2bf(tmp[j][0]);
      u32 hi = ((u32)f2bf(tmp[j][3]) << 16) | (u32)f2bf(tmp[j][2]);
      int byte = (row * 256 + c4 * 2) ^ ((row & 7) << 4);
      u32x2 val; val[0] = lo; val[1] = hi;
      *(u32x2*)((char*)As + byte) = val;
    }
  }
  __syncthreads();

  const int wave = tid >> 6, lane = tid & 63;
  const int wc = wave * 32;
  const int lr = lane & 15, lg = lane >> 4;

  s16x8 af[4][4];
#pragma unroll
  for (int ks = 0; ks < 4; ++ks) {
    int kb2 = (ks * 32 + lg * 8) * 2;
#pragma unroll
    for (int mt = 0; mt < 4; ++mt) {
      int row = mt * 16 + lr;
      int byte = (row * 256 + kb2) ^ ((row & 7) << 4);
      af[ks][mt] = *(const s16x8*)((const char*)As + byte);
    }
  }

  for (int w = 0; w < 3; ++w) {
    s16x8 bfr[4][2];
#pragma unroll
    for (int ks = 0; ks < 4; ++ks)
#pragma unroll
      for (int nt = 0; nt < 2; ++nt)
        bfr[ks][nt] = *(const s16x8*)(Wt + w * 16384 + (wc + nt * 16 + lr) * 128 + ks * 32 + lg * 8);

    f32x4 acc[4][2];
    for (int mt = 0; mt < 4; ++mt)
      for (int nt = 0; nt < 2; ++nt) acc[mt][nt] = {0.f, 0.f, 0.f, 0.f};

#pragma unroll
    for (int ks = 0; ks < 4; ++ks)
      for (int mt = 0; mt < 4; ++mt)
        for (int nt = 0; nt < 2; ++nt)
          acc[mt][nt] = __builtin_amdgcn_mfma_f32_16x16x32_bf16(af[ks][mt], bfr[ks][nt], acc[mt][nt], 0, 0, 0);

    if (w == 2) {
      for (int mt = 0; mt < 4; ++mt) {
        for (int r = 0; r < 4; ++r) {
          long row = brow + mt * 16 + lg * 4 + r;
          if (row < M) {
            u32 val = (u32)f2bf(acc[mt][0][r]) | ((u32)f2bf(acc[mt][1][r]) << 16);
            vb2[row * 64 + wave * 16 + lr] = val;
          }
        }
      }
    } else {
      u16* C = (w == 0) ? qb : kb;
      for (int mt = 0; mt < 4; ++mt) {
        for (int nt = 0; nt < 2; ++nt) {
          int col = wc + nt * 16 + lr;
          for (int r = 0; r < 4; ++r) {
            long row = brow + mt * 16 + lg * 4 + r;
            if (row < M) C[row * 128 + col] = f2bf(acc[mt][nt][r]);
          }
        }
      }
    }
  }
}

// ---------- stage 6: e-GEMM, 64-row tile, fragment scatter store ----------
__global__ __launch_bounds__(256) void roen_gemm_e(const float* __restrict__ ea,
                                                   const u16* __restrict__ WtE,
                                                   const int* __restrict__ inv,
                                                   u32* __restrict__ eS2, int E,
                                                   float* __restrict__ dbg) {
  __shared__ u16 As[64 * 128];
  __shared__ int invv[64];
  const int tid = threadIdx.x;
  if (blockIdx.x == 0 && tid == 0) dbg[6] = 1006.0f;
  const long brow = (long)blockIdx.x * 64;

  if (tid < 64) {
    long pos = brow + tid;
    invv[tid] = (pos < E) ? inv[pos] : -1;
  }

  {
    f32x4 tmp[8];
#pragma unroll
    for (int j = 0; j < 8; ++j) {
      int idx = j * 256 + tid;
      int row = idx >> 5;
      int c4 = (idx & 31) * 4;
      long grow = brow + row;
      f32x4 a = {0.f, 0.f, 0.f, 0.f};
      if (grow < E) a = *(const f32x4*)(ea + grow * 128 + c4);
      tmp[j] = a;
    }
#pragma unroll
    for (int j = 0; j < 8; ++j) {
      int idx = j * 256 + tid;
      int row = idx >> 5;
      int c4 = (idx & 31) * 4;
      u32 lo = ((u32)f2bf(tmp[j][1]) << 16) | (u32)f2bf(tmp[j][0]);
      u32 hi = ((u32)f2bf(tmp[j][3]) << 16) | (u32)f2bf(tmp[j][2]);
      int byte = (row * 256 + c4 * 2) ^ ((row & 7) << 4);
      u32x2 val; val[0] = lo; val[1] = hi;
      *(u32x2*)((char*)As + byte) = val;
    }
  }
  __syncthreads();

  const int wave = tid >> 6, lane = tid & 63;
  const int wc = wave * 32;
  const int lr = lane & 15, lg = lane >> 4;

  s16x8 bfr[4][2];
#pragma unroll
  for (int ks = 0; ks < 4; ++ks)
#pragma unroll
    for (int nt = 0; nt < 2; ++nt)
      bfr[ks][nt] = *(const s16x8*)(WtE + (wc + nt * 16 + lr) * 128 + ks * 32 + lg * 8);

  f32x4 acc[4][2];
  for (int mt = 0; mt < 4; ++mt)
    for (int nt = 0; nt < 2; ++nt) acc[mt][nt] = {0.f, 0.f, 0.f, 0.f};

  for (int ks = 0; ks < 4; ++ks) {
    int kb2 = (ks * 32 + lg * 8) * 2;
    s16x8 af[4];
    for (int mt = 0; mt < 4; ++mt) {
      int row = mt * 16 + lr;
      int byte = (row * 256 + kb2) ^ ((row & 7) << 4);
      af[mt] = *(const s16x8*)((const char*)As + byte);
    }
    for (int mt = 0; mt < 4; ++mt)
      for (int nt = 0; nt < 2; ++nt)
        acc[mt][nt] = __builtin_amdgcn_mfma_f32_16x16x32_bf16(af[mt], bfr[ks][nt], acc[mt][nt], 0, 0, 0);
  }

  for (int mt = 0; mt < 4; ++mt) {
    for (int r = 0; r < 4; ++r) {
      int row = mt * 16 + lg * 4 + r;
      int op = invv[row];
      if (op >= 0) {
        u32 val = (u32)f2bf(acc[mt][0][r]) | ((u32)f2bf(acc[mt][1][r]) << 16);
        eS2[(long)op * 64 + wave * 16 + lr] = val;
      }
    }
  }
}

// ---------- stage 9: FUSED score + aggregation, wave per node ----------
// Per 8-edge chunk: score phase lane=(eidx,head) fully parallel (in-lane 16-dim
// dot + exp); agg phase lane=dim-mapped, w via 2 __shfl/edge. No barriers.
__global__ __launch_bounds__(256) void roen_agg(const int* __restrict__ off,
                                                const int* __restrict__ srcS,
                                                const u16* __restrict__ qb,
                                                const u16* __restrict__ kb,
                                                const u32* __restrict__ eS2,
                                                const u32* __restrict__ vb2,
                                                float* __restrict__ outat, int N,
                                                float* __restrict__ dbg) {
  int wave = threadIdx.x >> 6;
  int lane = threadIdx.x & 63;
  int node = blockIdx.x * 4 + wave;
  if (node == 0 && lane == 0) dbg[9] = 1009.0f;
  if (node >= N) return;
  int beg = off[node], end = off[node + 1];

  // score-phase mapping: lane -> (edge slot eidx, head sh)
  const int eidx = lane >> 3;
  const int sh = lane & 7;
  const int g16 = (sh >> 1) * 16;      // u32 base for this head pair
  const int shv = (sh & 1) * 16;       // lo/hi within u32
  const s16x8* qp = (const s16x8*)(qb + (long)node * 128 + sh * 16);
  s16x8 q0 = qp[0], q1 = qp[1];

  // agg-phase mapping: lane -> dims dA, dB (heads hA, hA+1)
  const int dA = 32 * (lane >> 4) + (lane & 15);
  const int dB = dA + 16;
  const int hA = dA >> 4;              // even
  float accA = 0.f, accB = 0.f, dsA = 0.f, dsB = 0.f;

  for (int cbeg = beg; cbeg < end; cbeg += 8) {
    // ---- score phase (parallel over 8 edges x 8 heads) ----
    long spos = cbeg + eidx;
    float w = 0.f;
    if (spos < end) {
      int src = srcS[spos];
      const s16x8* kp = (const s16x8*)(kb + (long)src * 128 + sh * 16);
      s16x8 k0 = kp[0], k1 = kp[1];
      const u32x4* ep = (const u32x4*)(eS2 + spos * 64 + g16);
      u32x4 e0 = ep[0], e1 = ep[1], e2 = ep[2], e3 = ep[3];
      float acc = 0.f;
#pragma unroll
      for (int j = 0; j < 4; ++j) {
        acc += bf2f((u16)q0[j])     * (bf2f((u16)k0[j])     + bf2f((u16)(e0[j] >> shv)));
        acc += bf2f((u16)q0[j + 4]) * (bf2f((u16)k0[j + 4]) + bf2f((u16)(e1[j] >> shv)));
        acc += bf2f((u16)q1[j])     * (bf2f((u16)k1[j])     + bf2f((u16)(e2[j] >> shv)));
        acc += bf2f((u16)q1[j + 4]) * (bf2f((u16)k1[j + 4]) + bf2f((u16)(e3[j] >> shv)));
      }
      w = __expf(fminf(acc * 0.25f, 80.f));
    }

    // ---- agg phase (dims; eS2 rows are L1-hot from score phase) ----
    u32 evs[8], vvs[8];
#pragma unroll
    for (int i = 0; i < 8; ++i) {
      long pos = cbeg + i;
      bool ok = pos < end;
      int src = ok ? srcS[pos] : 0;
      evs[i] = ok ? eS2[pos * 64 + lane] : 0u;
      vvs[i] = ok ? vb2[(long)src * 64 + lane] : 0u;
    }
#pragma unroll
    for (int i = 0; i < 8; ++i) {
      float wA = __shfl(w, i * 8 + hA);
      float wB = __shfl(w, i * 8 + hA + 1);
      accA += wA * (bf2f((u16)evs[i]) + bf2f((u16)vvs[i]));
      accB += wB * (bf2f((u16)(evs[i] >> 16)) + bf2f((u16)(vvs[i] >> 16)));
      dsA += wA; dsB += wB;
    }
  }
  outat[(long)node * 128 + dA] = accA / (dsA + 1e-16f);
  outat[(long)node * 128 + dB] = accB / (dsB + 1e-16f);
}

// ---------- stage 11: out@Wout GEMM + FUSED h = .. + bout + x, block column sums ----------
__global__ __launch_bounds__(256) void roen_gemm_out(const float* __restrict__ A,
                                                     const u16* __restrict__ Wt,
                                                     const float* __restrict__ x,
                                                     const float* __restrict__ bo,
                                                     float* __restrict__ h,
                                                     float* __restrict__ psum,
                                                     float* __restrict__ psumsq, int M,
                                                     float* __restrict__ dbg) {
  __shared__ u16 As[64 * 128];
  const int tid = threadIdx.x;
  if (blockIdx.x == 0 && tid == 0) dbg[11] = 1011.0f;
  const long brow = (long)blockIdx.x * 64;

  {
    f32x4 tmp[8];
#pragma unroll
    for (int j = 0; j < 8; ++j) {
      int idx = j * 256 + tid;
      int row = idx >> 5;
      int c4 = (idx & 31) * 4;
      long grow = brow + row;
      f32x4 a = {0.f, 0.f, 0.f, 0.f};
      if (grow < M) a = *(const f32x4*)(A + grow * 128 + c4);
      tmp[j] = a;
    }
#pragma unroll
    for (int j = 0; j < 8; ++j) {
      int idx = j * 256 + tid;
      int row = idx >> 5;
      int c4 = (idx & 31) * 4;
      u32 lo = ((u32)f2bf(tmp[j][1]) << 16) | (u32)f2bf(tmp[j][0]);
      u32 hi = ((u32)f2bf(tmp[j][3]) << 16) | (u32)f2bf(tmp[j][2]);
      int byte = (row * 256 + c4 * 2) ^ ((row & 7) << 4);
      u32x2 val; val[0] = lo; val[1] = hi;
      *(u32x2*)((char*)As + byte) = val;
    }
  }

  const int wave = tid >> 6, lane = tid & 63;
  const int wc = wave * 32;
  const int lr = lane & 15, lg = lane >> 4;

  s16x8 bfr[4][2];
#pragma unroll
  for (int ks = 0; ks < 4; ++ks)
#pragma unroll
    for (int nt = 0; nt < 2; ++nt)
      bfr[ks][nt] = *(const s16x8*)(Wt + (wc + nt * 16 + lr) * 128 + ks * 32 + lg * 8);

  __syncthreads();

  f32x4 acc[4][2];
  for (int mt = 0; mt < 4; ++mt)
    for (int nt = 0; nt < 2; ++nt) acc[mt][nt] = {0.f, 0.f, 0.f, 0.f};

  for (int ks = 0; ks < 4; ++ks) {
    int kb2 = (ks * 32 + lg * 8) * 2;
    s16x8 af[4];
    for (int mt = 0; mt < 4; ++mt) {
      int row = mt * 16 + lr;
      int byte = (row * 256 + kb2) ^ ((row & 7) << 4);
      af[mt] = *(const s16x8*)((const char*)As + byte);
    }
    for (int mt = 0; mt < 4; ++mt)
      for (int nt = 0; nt < 2; ++nt)
        acc[mt][nt] = __builtin_amdgcn_mfma_f32_16x16x32_bf16(af[mt], bfr[ks][nt], acc[mt][nt], 0, 0, 0);
  }

  float b0 = bo[wc + lr];
  float b1 = bo[wc + 16 + lr];
  float cs[2] = {0.f, 0.f}, cs2[2] = {0.f, 0.f};
  for (int mt = 0; mt < 4; ++mt) {
    for (int nt = 0; nt < 2; ++nt) {
      int col = wc + nt * 16 + lr;
      float bb = (nt == 0) ? b0 : b1;
      for (int r = 0; r < 4; ++r) {
        long row = brow + mt * 16 + lg * 4 + r;
        if (row < M) {
          long idx = row * 128 + col;
          float val = acc[mt][nt][r] + bb + x[idx];
          h[idx] = val;
          cs[nt] += val;
          cs2[nt] += val * val;
        }
      }
    }
  }
#pragma unroll
  for (int nt = 0; nt < 2; ++nt) {
    cs[nt] += __shfl_xor(cs[nt], 16);
    cs[nt] += __shfl_xor(cs[nt], 32);
    cs2[nt] += __shfl_xor(cs2[nt], 16);
    cs2[nt] += __shfl_xor(cs2[nt], 32);
  }
  if (lg == 0) {
    int col0 = wc + lr;
    psum[(long)blockIdx.x * 128 + col0] = cs[0];
    psumsq[(long)blockIdx.x * 128 + col0] = cs2[0];
    psum[(long)blockIdx.x * 128 + col0 + 16] = cs[1];
    psumsq[(long)blockIdx.x * 128 + col0 + 16] = cs2[1];
  }
}

// ---------- stage 13: GraphNorm coefficients ----------
__global__ void roen_stats(const float* __restrict__ psum, const float* __restrict__ psumsq,
                           const float* __restrict__ gnw, const float* __restrict__ gnb,
                           const float* __restrict__ gnms, float* __restrict__ Ac,
                           float* __restrict__ Bc, int nb, int N, float* __restrict__ dbg) {
  int d = threadIdx.x;
  if (d == 0) dbg[13] = 1013.0f;
  float s = 0.f, s2 = 0.f;
  for (int i = 0; i < nb; ++i) {
    s += psum[(long)i * 128 + d];
    s2 += psumsq[(long)i * 128 + d];
  }
  float mean = s / (float)N;
  float mm = mean * gnms[d];
  float var = s2 / (float)N - 2.f * mm * mean + mm * mm;
  float scale = gnw[d] * rsqrtf(var + 1e-5f);
  Ac[d] = scale;
  Bc[d] = gnb[d] - mm * scale;
}

// ---------- final: normalize + exact GELU -> f32 out ----------
__global__ __launch_bounds__(256) void roen_final(const float* __restrict__ h,
                                                  const float* __restrict__ Ac,
                                                  const float* __restrict__ Bc,
                                                  float* __restrict__ out, long total) {
  long i = (long)blockIdx.x * 256 + threadIdx.x;
  if (i >= total) return;
  int d = (int)(i & 127);
  float v = h[i] * Ac[d] + Bc[d];
  out[i] = 0.5f * v * (1.f + erff(v * 0.70710678f));
}

extern "C" void kernel_launch(void* const* d_in, const int* in_sizes, int n_in,
                              void* d_out, int out_size, void* d_ws, size_t ws_size,
                              hipStream_t stream) {
  const float* x   = (const float*)d_in[0];
  const int*   ei  = (const int*)d_in[1];
  const float* ea  = (const float*)d_in[2];
  const float* WQ  = (const float*)d_in[3];
  const float* WK  = (const float*)d_in[4];
  const float* WV  = (const float*)d_in[5];
  const float* WE  = (const float*)d_in[6];
  const float* Wo  = (const float*)d_in[7];
  const float* bo  = (const float*)d_in[8];
  const float* gnw = (const float*)d_in[9];
  const float* gnb = (const float*)d_in[10];
  const float* gnms= (const float*)d_in[11];
  float* out = (float*)d_out;
  float* dbg = (float*)d_out;

  const int N = in_sizes[0] / 128;   // 20000
  const int E = in_sizes[1] / 2;     // 640000
  const int gN = (N + 63) / 64;

  char* base = (char*)d_ws;
  size_t cur = 0;
  auto alloc = [&](size_t bytes) -> char* {
    char* r = base + cur;
    cur = (cur + bytes + 255) & ~(size_t)255;
    return r;
  };
  u16*   wt     = (u16*)alloc(5 * 16384 * sizeof(u16));
  u16*   qb     = (u16*)alloc((size_t)N * 128 * sizeof(u16));
  u16*   kb     = (u16*)alloc((size_t)N * 128 * sizeof(u16));
  u32*   vb2    = (u32*)alloc((size_t)N * 64 * sizeof(u32));
  int*   count  = (int*)alloc((size_t)N * sizeof(int));
  int*   offar  = (int*)alloc((size_t)(N + 1) * sizeof(int));
  int*   rank   = (int*)alloc((size_t)E * sizeof(int));
  int*   invar  = (int*)alloc((size_t)E * sizeof(int));
  int*   srcS   = (int*)alloc((size_t)E * sizeof(int));
  float* outat  = (float*)alloc((size_t)N * 128 * sizeof(float));
  float* psum   = (float*)alloc((size_t)gN * 128 * sizeof(float));
  float* psumsq = (float*)alloc((size_t)gN * 128 * sizeof(float));
  float* Ac     = (float*)alloc(128 * sizeof(float));
  float* Bc     = (float*)alloc(128 * sizeof(float));
  u32*   eS2    = (u32*)alloc((size_t)E * 64 * sizeof(u32));  // 164 MB
  float* hbuf   = (float*)eS2;  // alias: eS2 dead after roen_agg

  roen_prep_w<<<5 + (N + 255) / 256, 256, 0, stream>>>(WQ, WK, WV, WE, Wo, wt, count, N, dbg);
  roen_hist<<<(E + 255) / 256, 256, 0, stream>>>(ei, E, count, rank, dbg);
  roen_scan<<<1, 1024, 0, stream>>>(count, N, offar, dbg);
  roen_scatter<<<(E + 255) / 256, 256, 0, stream>>>(ei, offar, rank, E, invar, srcS, dbg);

  roen_gemm_qkv<<<gN, 256, 0, stream>>>(x, wt, qb, kb, vb2, N, dbg);
  roen_gemm_e<<<(E + 63) / 64, 256, 0, stream>>>(ea, wt + 3 * 16384, invar, eS2, E, dbg);

  roen_agg<<<(N + 3) / 4, 256, 0, stream>>>(offar, srcS, qb, kb, eS2, vb2, outat, N, dbg);

  roen_gemm_out<<<gN, 256, 0, stream>>>(outat, wt + 4 * 16384, x, bo, hbuf, psum, psumsq, N, dbg);
  roen_stats<<<1, 128, 0, stream>>>(psum, psumsq, gnw, gnb, gnms, Ac, Bc, gN, N, dbg);
  roen_final<<<(int)(((long)N * 128 + 255) / 256), 256, 0, stream>>>(hbuf, Ac, Bc, out, (long)N * 128);
}

// Round 13
// 414.258 us; speedup vs baseline: 1.0550x; 1.0550x over previous
//
#include <hip/hip_runtime.h>

using u16 = unsigned short;
using u32 = unsigned int;
typedef float f32x4 __attribute__((ext_vector_type(4)));
typedef float f32x2 __attribute__((ext_vector_type(2)));
typedef short s16x8 __attribute__((ext_vector_type(8)));
typedef u32   u32x2 __attribute__((ext_vector_type(2)));
typedef u32   u32x4 __attribute__((ext_vector_type(4)));

__device__ __forceinline__ u16 f2bf(float f) {
  u32 u = __float_as_uint(f);
  u += 0x7fffu + ((u >> 16) & 1u);
  return (u16)(u >> 16);
}
__device__ __forceinline__ float bf2f(u16 h) {
  return __uint_as_float(((u32)h) << 16);
}

__global__ void ROEN_Final_33526514713351_kernel() {}

// Fragment layout for eS2/vb2: row r, u32 j in [0,64): lo16 = dim 32*(j>>4)+(j&15),
// hi16 = that dim + 16.  Head h lives at u32s (h>>1)*16+j with shift (h&1)*16.

// ---------- stage 0+4: weight prep (blocks 0-4) + count zero (blocks 5+) ----------
__global__ void roen_prep_w(const float* __restrict__ W0, const float* __restrict__ W1,
                            const float* __restrict__ W2, const float* __restrict__ W3,
                            const float* __restrict__ W4, u16* __restrict__ Wt,
                            int* __restrict__ count, int N, float* __restrict__ dbg) {
  int b = blockIdx.x;
  if (b < 5) {
    if (b == 0 && threadIdx.x == 0) dbg[4] = 1004.0f;
    const float* W = (b == 0) ? W0 : (b == 1) ? W1 : (b == 2) ? W2 : (b == 3) ? W3 : W4;
    for (int idx = threadIdx.x; idx < 16384; idx += 256) {
      int n = idx >> 7, k = idx & 127;
      Wt[b * 16384 + idx] = f2bf(W[k * 128 + n]);
    }
  } else {
    int i = (b - 5) * 256 + threadIdx.x;
    if (i == 0) dbg[0] = 1000.0f;
    if (i < N) count[i] = 0;
  }
}

// ---------- stage 1: histogram + per-edge rank ----------
__global__ void roen_hist(const int* __restrict__ ei, int E, int* __restrict__ count,
                          int* __restrict__ rank, float* __restrict__ dbg) {
  int i = blockIdx.x * 256 + threadIdx.x;
  if (i == 0) dbg[1] = 1001.0f;
  if (i < E) rank[i] = atomicAdd(&count[ei[E + i]], 1);
}

// ---------- stage 2: exclusive scan, coalesced 1024-wide tiles + wave shfl-scan ----------
__global__ __launch_bounds__(1024) void roen_scan(const int* __restrict__ count, int N,
                                                  int* __restrict__ off,
                                                  float* __restrict__ dbg) {
  __shared__ int wsum[16];
  __shared__ int carrys;
  int tid = threadIdx.x, lane = tid & 63, wv = tid >> 6;
  if (tid == 0) { dbg[2] = 1002.0f; carrys = 0; }
  __syncthreads();
  for (int base = 0; base < N; base += 1024) {
    int i = base + tid;
    int v = (i < N) ? count[i] : 0;
    int x = v;
#pragma unroll
    for (int s = 1; s < 64; s <<= 1) {
      int t = __shfl_up(x, s);
      if (lane >= s) x += t;
    }
    if (lane == 63) wsum[wv] = x;
    __syncthreads();
    if (wv == 0 && lane < 16) {
      int y = wsum[lane];
#pragma unroll
      for (int s = 1; s < 16; s <<= 1) {
        int t = __shfl_up(y, s);
        if (lane >= s) y += t;
      }
      wsum[lane] = y;
    }
    __syncthreads();
    int wbase = (wv == 0) ? 0 : wsum[wv - 1];
    int incl = x + wbase + carrys;
    if (i < N) off[i] = incl - v;
    __syncthreads();
    if (tid == 1023) carrys = incl;
    __syncthreads();
  }
  if (tid == 0) off[N] = carrys;
}

// ---------- stage 3: scatter without atomics: pos = off[dst] + rank ----------
__global__ void roen_scatter(const int* __restrict__ ei, const int* __restrict__ off,
                             const int* __restrict__ rank, int E,
                             int* __restrict__ inv, int* __restrict__ srcS,
                             int* __restrict__ dstS, float* __restrict__ dbg) {
  int i = blockIdx.x * 256 + threadIdx.x;
  if (i == 0) dbg[3] = 1003.0f;
  if (i < E) {
    int d = ei[E + i];
    int p = off[d] + rank[i];
    inv[i] = p;
    srcS[p] = ei[i];
    dstS[p] = d;
  }
}

// ---------- stage 5: fused q/k/v GEMM; q,k row layout, v fragment layout ----------
__global__ __launch_bounds__(256) void roen_gemm_qkv(const float* __restrict__ x,
                                                     const u16* __restrict__ Wt,
                                                     u16* __restrict__ qb, u16* __restrict__ kb,
                                                     u32* __restrict__ vb2, int M,
                                                     float* __restrict__ dbg) {
  __shared__ u16 As[64 * 128];
  const int tid = threadIdx.x;
  if (blockIdx.x == 0 && tid == 0) dbg[5] = 1005.0f;
  const long brow = (long)blockIdx.x * 64;

  {
    f32x4 tmp[8];
#pragma unroll
    for (int j = 0; j < 8; ++j) {
      int idx = j * 256 + tid;
      int row = idx >> 5;
      int c4 = (idx & 31) * 4;
      long grow = brow + row;
      f32x4 a = {0.f, 0.f, 0.f, 0.f};
      if (grow < M) a = *(const f32x4*)(x + grow * 128 + c4);
      tmp[j] = a;
    }
#pragma unroll
    for (int j = 0; j < 8; ++j) {
      int idx = j * 256 + tid;
      int row = idx >> 5;
      int c4 = (idx & 31) * 4;
      u32 lo = ((u32)f2bf(tmp[j][1]) << 16) | (u32)f2bf(tmp[j][0]);
      u32 hi = ((u32)f2bf(tmp[j][3]) << 16) | (u32)f2bf(tmp[j][2]);
      int byte = (row * 256 + c4 * 2) ^ ((row & 7) << 4);
      u32x2 val; val[0] = lo; val[1] = hi;
      *(u32x2*)((char*)As + byte) = val;
    }
  }
  __syncthreads();

  const int wave = tid >> 6, lane = tid & 63;
  const int wc = wave * 32;
  const int lr = lane & 15, lg = lane >> 4;

  s16x8 af[4][4];
#pragma unroll
  for (int ks = 0; ks < 4; ++ks) {
    int kb2 = (ks * 32 + lg * 8) * 2;
#pragma unroll
    for (int mt = 0; mt < 4; ++mt) {
      int row = mt * 16 + lr;
      int byte = (row * 256 + kb2) ^ ((row & 7) << 4);
      af[ks][mt] = *(const s16x8*)((const char*)As + byte);
    }
  }

  for (int w = 0; w < 3; ++w) {
    s16x8 bfr[4][2];
#pragma unroll
    for (int ks = 0; ks < 4; ++ks)
#pragma unroll
      for (int nt = 0; nt < 2; ++nt)
        bfr[ks][nt] = *(const s16x8*)(Wt + w * 16384 + (wc + nt * 16 + lr) * 128 + ks * 32 + lg * 8);

    f32x4 acc[4][2];
    for (int mt = 0; mt < 4; ++mt)
      for (int nt = 0; nt < 2; ++nt) acc[mt][nt] = {0.f, 0.f, 0.f, 0.f};

#pragma unroll
    for (int ks = 0; ks < 4; ++ks)
      for (int mt = 0; mt < 4; ++mt)
        for (int nt = 0; nt < 2; ++nt)
          acc[mt][nt] = __builtin_amdgcn_mfma_f32_16x16x32_bf16(af[ks][mt], bfr[ks][nt], acc[mt][nt], 0, 0, 0);

    if (w == 2) {
      for (int mt = 0; mt < 4; ++mt) {
        for (int r = 0; r < 4; ++r) {
          long row = brow + mt * 16 + lg * 4 + r;
          if (row < M) {
            u32 val = (u32)f2bf(acc[mt][0][r]) | ((u32)f2bf(acc[mt][1][r]) << 16);
            vb2[row * 64 + wave * 16 + lr] = val;
          }
        }
      }
    } else {
      u16* C = (w == 0) ? qb : kb;
      for (int mt = 0; mt < 4; ++mt) {
        for (int nt = 0; nt < 2; ++nt) {
          int col = wc + nt * 16 + lr;
          for (int r = 0; r < 4; ++r) {
            long row = brow + mt * 16 + lg * 4 + r;
            if (row < M) C[row * 128 + col] = f2bf(acc[mt][nt][r]);
          }
        }
      }
    }
  }
}

// ---------- stage 6: e-GEMM, 64-row tile, fragment scatter store ----------
__global__ __launch_bounds__(256) void roen_gemm_e(const float* __restrict__ ea,
                                                   const u16* __restrict__ WtE,
                                                   const int* __restrict__ inv,
                                                   u32* __restrict__ eS2, int E,
                                                   float* __restrict__ dbg) {
  __shared__ u16 As[64 * 128];
  __shared__ int invv[64];
  const int tid = threadIdx.x;
  if (blockIdx.x == 0 && tid == 0) dbg[6] = 1006.0f;
  const long brow = (long)blockIdx.x * 64;

  if (tid < 64) {
    long pos = brow + tid;
    invv[tid] = (pos < E) ? inv[pos] : -1;
  }

  {
    f32x4 tmp[8];
#pragma unroll
    for (int j = 0; j < 8; ++j) {
      int idx = j * 256 + tid;
      int row = idx >> 5;
      int c4 = (idx & 31) * 4;
      long grow = brow + row;
      f32x4 a = {0.f, 0.f, 0.f, 0.f};
      if (grow < E) a = *(const f32x4*)(ea + grow * 128 + c4);
      tmp[j] = a;
    }
#pragma unroll
    for (int j = 0; j < 8; ++j) {
      int idx = j * 256 + tid;
      int row = idx >> 5;
      int c4 = (idx & 31) * 4;
      u32 lo = ((u32)f2bf(tmp[j][1]) << 16) | (u32)f2bf(tmp[j][0]);
      u32 hi = ((u32)f2bf(tmp[j][3]) << 16) | (u32)f2bf(tmp[j][2]);
      int byte = (row * 256 + c4 * 2) ^ ((row & 7) << 4);
      u32x2 val; val[0] = lo; val[1] = hi;
      *(u32x2*)((char*)As + byte) = val;
    }
  }
  __syncthreads();

  const int wave = tid >> 6, lane = tid & 63;
  const int wc = wave * 32;
  const int lr = lane & 15, lg = lane >> 4;

  s16x8 bfr[4][2];
#pragma unroll
  for (int ks = 0; ks < 4; ++ks)
#pragma unroll
    for (int nt = 0; nt < 2; ++nt)
      bfr[ks][nt] = *(const s16x8*)(WtE + (wc + nt * 16 + lr) * 128 + ks * 32 + lg * 8);

  f32x4 acc[4][2];
  for (int mt = 0; mt < 4; ++mt)
    for (int nt = 0; nt < 2; ++nt) acc[mt][nt] = {0.f, 0.f, 0.f, 0.f};

  for (int ks = 0; ks < 4; ++ks) {
    int kb2 = (ks * 32 + lg * 8) * 2;
    s16x8 af[4];
    for (int mt = 0; mt < 4; ++mt) {
      int row = mt * 16 + lr;
      int byte = (row * 256 + kb2) ^ ((row & 7) << 4);
      af[mt] = *(const s16x8*)((const char*)As + byte);
    }
    for (int mt = 0; mt < 4; ++mt)
      for (int nt = 0; nt < 2; ++nt)
        acc[mt][nt] = __builtin_amdgcn_mfma_f32_16x16x32_bf16(af[mt], bfr[ks][nt], acc[mt][nt], 0, 0, 0);
  }

  for (int mt = 0; mt < 4; ++mt) {
    for (int r = 0; r < 4; ++r) {
      int row = mt * 16 + lg * 4 + r;
      int op = invv[row];
      if (op >= 0) {
        u32 val = (u32)f2bf(acc[mt][0][r]) | ((u32)f2bf(acc[mt][1][r]) << 16);
        eS2[(long)op * 64 + wave * 16 + lr] = val;
      }
    }
  }
}

// ---------- stage 9: score -> w = exp(min(s/4,80)), sorted order, E x 8 parallel ----------
__global__ __launch_bounds__(256) void roen_score(const int* __restrict__ srcS,
                                                  const int* __restrict__ dstS,
                                                  const u16* __restrict__ qb,
                                                  const u16* __restrict__ kb,
                                                  const u32* __restrict__ eS2,
                                                  float* __restrict__ wS, int E,
                                                  float* __restrict__ dbg) {
  long gid = (long)blockIdx.x * 256 + threadIdx.x;
  if (gid == 0) dbg[9] = 1009.0f;
  long pos = gid >> 3;
  int h = (int)(gid & 7);
  if (pos >= E) return;
  int dst = dstS[pos], src = srcS[pos];
  const s16x8* qp = (const s16x8*)(qb + (long)dst * 128 + h * 16);
  const s16x8* kp = (const s16x8*)(kb + (long)src * 128 + h * 16);
  const u32x4* ep = (const u32x4*)(eS2 + (long)pos * 64 + (h >> 1) * 16);
  const int sh = (h & 1) * 16;
  float acc = 0.f;
#pragma unroll
  for (int c = 0; c < 2; ++c) {
    s16x8 qv = qp[c], kv = kp[c];
    u32x4 ea_ = ep[c * 2], eb_ = ep[c * 2 + 1];
#pragma unroll
    for (int j = 0; j < 4; ++j) {
      float e0 = bf2f((u16)(ea_[j] >> sh));
      float e1 = bf2f((u16)(eb_[j] >> sh));
      acc += bf2f((u16)qv[j]) * (bf2f((u16)kv[j]) + e0);
      acc += bf2f((u16)qv[j + 4]) * (bf2f((u16)kv[j + 4]) + e1);
    }
  }
  wS[pos * 8 + h] = __expf(fminf(acc * 0.25f, 80.f));
}

// ---------- stage 10: per-node aggregation, fragment layout, 8-wide pipelined ----------
__global__ __launch_bounds__(256) void roen_node_agg(const int* __restrict__ off,
                                                     const int* __restrict__ srcS,
                                                     const u32* __restrict__ eS2,
                                                     const u32* __restrict__ vb2,
                                                     const float* __restrict__ wS,
                                                     u16* __restrict__ outat, int N,
                                                     float* __restrict__ dbg) {
  int wave = threadIdx.x >> 6;
  int lane = threadIdx.x & 63;
  int node = blockIdx.x * 4 + wave;
  if (node == 0 && lane == 0) dbg[10] = 1010.0f;
  if (node >= N) return;
  int beg = off[node], end = off[node + 1];

  const int dA = 32 * (lane >> 4) + (lane & 15);
  const int dB = dA + 16;
  const int hA = dA >> 4;   // even
  float accA = 0.f, accB = 0.f, dsA = 0.f, dsB = 0.f;

  int pos = beg;
  for (; pos + 8 <= end; pos += 8) {
    int ss[8];
    f32x2 w[8];
    u32 ev[8], vv[8];
#pragma unroll
    for (int i = 0; i < 8; ++i) ss[i] = srcS[pos + i];
#pragma unroll
    for (int i = 0; i < 8; ++i) w[i] = *(const f32x2*)(wS + (long)(pos + i) * 8 + hA);
#pragma unroll
    for (int i = 0; i < 8; ++i) ev[i] = eS2[(long)(pos + i) * 64 + lane];
#pragma unroll
    for (int i = 0; i < 8; ++i) vv[i] = vb2[(long)ss[i] * 64 + lane];
#pragma unroll
    for (int i = 0; i < 8; ++i) {
      accA += w[i][0] * (bf2f((u16)vv[i]) + bf2f((u16)ev[i]));
      accB += w[i][1] * (bf2f((u16)(vv[i] >> 16)) + bf2f((u16)(ev[i] >> 16)));
      dsA += w[i][0]; dsB += w[i][1];
    }
  }
  for (; pos < end; ++pos) {
    f32x2 w = *(const f32x2*)(wS + (long)pos * 8 + hA);
    u32 ev = eS2[(long)pos * 64 + lane];
    int src = srcS[pos];
    u32 vv = vb2[(long)src * 64 + lane];
    accA += w[0] * (bf2f((u16)vv) + bf2f((u16)ev));
    accB += w[1] * (bf2f((u16)(vv >> 16)) + bf2f((u16)(ev >> 16)));
    dsA += w[0]; dsB += w[1];
  }
  outat[(long)node * 128 + dA] = f2bf(accA / (dsA + 1e-16f));
  outat[(long)node * 128 + dB] = f2bf(accB / (dsB + 1e-16f));
}

// ---------- stage 11: out@Wout GEMM (bf16 A) + FUSED h = .. + bout + x, block sums ----------
__global__ __launch_bounds__(256) void roen_gemm_out(const u16* __restrict__ A,
                                                     const u16* __restrict__ Wt,
                                                     const float* __restrict__ x,
                                                     const float* __restrict__ bo,
                                                     float* __restrict__ h,
                                                     float* __restrict__ psum,
                                                     float* __restrict__ psumsq, int M,
                                                     float* __restrict__ dbg) {
  __shared__ u16 As[64 * 128];
  const int tid = threadIdx.x;
  if (blockIdx.x == 0 && tid == 0) dbg[11] = 1011.0f;
  const long brow = (long)blockIdx.x * 64;

  // stage bf16 A directly (no conversion): 1024 s16x8 granules
#pragma unroll
  for (int j = 0; j < 4; ++j) {
    int idx = j * 256 + tid;
    int row = idx >> 4;
    int c8 = (idx & 15) * 8;
    long grow = brow + row;
    s16x8 val = {0, 0, 0, 0, 0, 0, 0, 0};
    if (grow < M) val = *(const s16x8*)(A + grow * 128 + c8);
    int byte = (row * 256 + c8 * 2) ^ ((row & 7) << 4);
    *(s16x8*)((char*)As + byte) = val;
  }

  const int wave = tid >> 6, lane = tid & 63;
  const int wc = wave * 32;
  const int lr = lane & 15, lg = lane >> 4;

  s16x8 bfr[4][2];
#pragma unroll
  for (int ks = 0; ks < 4; ++ks)
#pragma unroll
    for (int nt = 0; nt < 2; ++nt)
      bfr[ks][nt] = *(const s16x8*)(Wt + (wc + nt * 16 + lr) * 128 + ks * 32 + lg * 8);

  __syncthreads();

  f32x4 acc[4][2];
  for (int mt = 0; mt < 4; ++mt)
    for (int nt = 0; nt < 2; ++nt) acc[mt][nt] = {0.f, 0.f, 0.f, 0.f};

  for (int ks = 0; ks < 4; ++ks) {
    int kb2 = (ks * 32 + lg * 8) * 2;
    s16x8 af[4];
    for (int mt = 0; mt < 4; ++mt) {
      int row = mt * 16 + lr;
      int byte = (row * 256 + kb2) ^ ((row & 7) << 4);
      af[mt] = *(const s16x8*)((const char*)As + byte);
    }
    for (int mt = 0; mt < 4; ++mt)
      for (int nt = 0; nt < 2; ++nt)
        acc[mt][nt] = __builtin_amdgcn_mfma_f32_16x16x32_bf16(af[mt], bfr[ks][nt], acc[mt][nt], 0, 0, 0);
  }

  float b0 = bo[wc + lr];
  float b1 = bo[wc + 16 + lr];
  float cs[2] = {0.f, 0.f}, cs2[2] = {0.f, 0.f};
  for (int mt = 0; mt < 4; ++mt) {
    for (int nt = 0; nt < 2; ++nt) {
      int col = wc + nt * 16 + lr;
      float bb = (nt == 0) ? b0 : b1;
      for (int r = 0; r < 4; ++r) {
        long row = brow + mt * 16 + lg * 4 + r;
        if (row < M) {
          long idx = row * 128 + col;
          float val = acc[mt][nt][r] + bb + x[idx];
          h[idx] = val;
          cs[nt] += val;
          cs2[nt] += val * val;
        }
      }
    }
  }
#pragma unroll
  for (int nt = 0; nt < 2; ++nt) {
    cs[nt] += __shfl_xor(cs[nt], 16);
    cs[nt] += __shfl_xor(cs[nt], 32);
    cs2[nt] += __shfl_xor(cs2[nt], 16);
    cs2[nt] += __shfl_xor(cs2[nt], 32);
  }
  if (lg == 0) {
    int col0 = wc + lr;
    psum[(long)blockIdx.x * 128 + col0] = cs[0];
    psumsq[(long)blockIdx.x * 128 + col0] = cs2[0];
    psum[(long)blockIdx.x * 128 + col0 + 16] = cs[1];
    psumsq[(long)blockIdx.x * 128 + col0 + 16] = cs2[1];
  }
}

// ---------- stage 13: GraphNorm coefficients ----------
__global__ void roen_stats(const float* __restrict__ psum, const float* __restrict__ psumsq,
                           const float* __restrict__ gnw, const float* __restrict__ gnb,
                           const float* __restrict__ gnms, float* __restrict__ Ac,
                           float* __restrict__ Bc, int nb, int N, float* __restrict__ dbg) {
  int d = threadIdx.x;
  if (d == 0) dbg[13] = 1013.0f;
  float s = 0.f, s2 = 0.f;
  for (int i = 0; i < nb; ++i) {
    s += psum[(long)i * 128 + d];
    s2 += psumsq[(long)i * 128 + d];
  }
  float mean = s / (float)N;
  float mm = mean * gnms[d];
  float var = s2 / (float)N - 2.f * mm * mean + mm * mm;
  float scale = gnw[d] * rsqrtf(var + 1e-5f);
  Ac[d] = scale;
  Bc[d] = gnb[d] - mm * scale;
}

// ---------- final: normalize + exact GELU -> f32 out ----------
__global__ __launch_bounds__(256) void roen_final(const float* __restrict__ h,
                                                  const float* __restrict__ Ac,
                                                  const float* __restrict__ Bc,
                                                  float* __restrict__ out, long total) {
  long i = (long)blockIdx.x * 256 + threadIdx.x;
  if (i >= total) return;
  int d = (int)(i & 127);
  float v = h[i] * Ac[d] + Bc[d];
  out[i] = 0.5f * v * (1.f + erff(v * 0.70710678f));
}

extern "C" void kernel_launch(void* const* d_in, const int* in_sizes, int n_in,
                              void* d_out, int out_size, void* d_ws, size_t ws_size,
                              hipStream_t stream) {
  const float* x   = (const float*)d_in[0];
  const int*   ei  = (const int*)d_in[1];
  const float* ea  = (const float*)d_in[2];
  const float* WQ  = (const float*)d_in[3];
  const float* WK  = (const float*)d_in[4];
  const float* WV  = (const float*)d_in[5];
  const float* WE  = (const float*)d_in[6];
  const float* Wo  = (const float*)d_in[7];
  const float* bo  = (const float*)d_in[8];
  const float* gnw = (const float*)d_in[9];
  const float* gnb = (const float*)d_in[10];
  const float* gnms= (const float*)d_in[11];
  float* out = (float*)d_out;
  float* dbg = (float*)d_out;

  const int N = in_sizes[0] / 128;   // 20000
  const int E = in_sizes[1] / 2;     // 640000
  const int gN = (N + 63) / 64;

  char* base = (char*)d_ws;
  size_t cur = 0;
  auto alloc = [&](size_t bytes) -> char* {
    char* r = base + cur;
    cur = (cur + bytes + 255) & ~(size_t)255;
    return r;
  };
  u16*   wt     = (u16*)alloc(5 * 16384 * sizeof(u16));
  u16*   qb     = (u16*)alloc((size_t)N * 128 * sizeof(u16));
  u16*   kb     = (u16*)alloc((size_t)N * 128 * sizeof(u16));
  u32*   vb2    = (u32*)alloc((size_t)N * 64 * sizeof(u32));
  float* wS     = (float*)alloc((size_t)E * 8 * sizeof(float));
  int*   count  = (int*)alloc((size_t)N * sizeof(int));
  int*   offar  = (int*)alloc((size_t)(N + 1) * sizeof(int));
  int*   rank   = (int*)alloc((size_t)E * sizeof(int));
  int*   invar  = (int*)alloc((size_t)E * sizeof(int));
  int*   srcS   = (int*)alloc((size_t)E * sizeof(int));
  int*   dstS   = (int*)alloc((size_t)E * sizeof(int));
  u16*   outat  = (u16*)alloc((size_t)N * 128 * sizeof(u16));
  float* psum   = (float*)alloc((size_t)gN * 128 * sizeof(float));
  float* psumsq = (float*)alloc((size_t)gN * 128 * sizeof(float));
  float* Ac     = (float*)alloc(128 * sizeof(float));
  float* Bc     = (float*)alloc(128 * sizeof(float));
  u32*   eS2    = (u32*)alloc((size_t)E * 64 * sizeof(u32));  // 164 MB
  float* hbuf   = (float*)eS2;  // alias: eS2 dead after node_agg

  roen_prep_w<<<5 + (N + 255) / 256, 256, 0, stream>>>(WQ, WK, WV, WE, Wo, wt, count, N, dbg);
  roen_hist<<<(E + 255) / 256, 256, 0, stream>>>(ei, E, count, rank, dbg);
  roen_scan<<<1, 1024, 0, stream>>>(count, N, offar, dbg);
  roen_scatter<<<(E + 255) / 256, 256, 0, stream>>>(ei, offar, rank, E, invar, srcS, dstS, dbg);

  roen_gemm_qkv<<<gN, 256, 0, stream>>>(x, wt, qb, kb, vb2, N, dbg);
  roen_gemm_e<<<(E + 63) / 64, 256, 0, stream>>>(ea, wt + 3 * 16384, invar, eS2, E, dbg);

  roen_score<<<(int)(((long)E * 8 + 255) / 256), 256, 0, stream>>>(srcS, dstS, qb, kb, eS2, wS, E, dbg);
  roen_node_agg<<<(N + 3) / 4, 256, 0, stream>>>(offar, srcS, eS2, vb2, wS, outat, N, dbg);

  roen_gemm_out<<<gN, 256, 0, stream>>>(outat, wt + 4 * 16384, x, bo, hbuf, psum, psumsq, N, dbg);
  roen_stats<<<1, 128, 0, stream>>>(psum, psumsq, gnw, gnb, gnms, Ac, Bc, gN, N, dbg);
  roen_final<<<(int)(((long)N * 128 + 255) / 256), 256, 0, stream>>>(hbuf, Ac, Bc, out, (long)N * 128);
}